// Round 19
// baseline (124.073 us; speedup 1.0000x reference)
//
#include <hip/hip_runtime.h>

// MHA forward: qkv GEMM -> flash attention -> proj GEMM. B=2,N=2048,C=1024,H=16,D=64.
// R19: attn KVBLK 64 -> 128: each counted-vmcnt super-tile stages 2 K + 2 V
//      sub-tiles (all in the proven [64][64] layout) and runs COMPUTE_KV twice
//      per barrier pair -> sync overhead per key halves. LDS 80KB, 2 blocks/CU
//      (= grid), 16 super-iters. GEMM (R16) and split unchanged.

typedef unsigned short u16;
typedef __attribute__((ext_vector_type(8))) _Float16 f16x8;
typedef __attribute__((ext_vector_type(2))) __fp16 fp16x2;
typedef __attribute__((ext_vector_type(4))) float f32x4;

#define DEV static __device__ __forceinline__
#define MFMA16(a, b, c) __builtin_amdgcn_mfma_f32_16x16x32_f16(a, b, c, 0, 0, 0)

DEV u16 f2h(float f) { _Float16 h = (_Float16)f; return __builtin_bit_cast(u16, h); }
DEV float h2f(u16 u) { return (float)__builtin_bit_cast(_Float16, u); }
DEV unsigned pkrtz(float a, float b) {
  fp16x2 h2 = __builtin_amdgcn_cvt_pkrtz(a, b);
  return __builtin_bit_cast(unsigned, h2);
}

DEV void async16(u16* dst, const u16* src) {
  __builtin_amdgcn_global_load_lds(
      (const __attribute__((address_space(1))) unsigned int*)(const void*)src,
      (__attribute__((address_space(3))) unsigned int*)(void*)dst, 16, 0, 0);
}

// ---------------- split fp32 -> fp16 hi (all three inputs) ----------------
__global__ __launch_bounds__(256) void k_split_all(
    const float* __restrict__ x, const float* __restrict__ wq,
    const float* __restrict__ wp, u16* __restrict__ xh,
    u16* __restrict__ wqh, u16* __restrict__ wph) {
  int i = blockIdx.x * 256 + threadIdx.x;
  const float* src;
  u16* dh;
  int off;
  if (i < 1048576) { src = x;  dh = xh;  off = i; }
  else if (i < 1835008) { src = wq; dh = wqh; off = i - 1048576; }
  else { src = wp; dh = wph; off = i - 1835008; }
  float4 v = ((const float4*)src)[off];
  ushort4 h;
  h.x = f2h(v.x); h.y = f2h(v.y); h.z = f2h(v.z); h.w = f2h(v.w);
  ((ushort4*)dh)[off] = h;
}

// ---------------- GEMM: C[M][N] = A[M][1024] . B[N][1024]^T + bias ----------------
// 128x128 tile, BK=64, 8 waves (4x2 grid, 32x64 per wave), pure fp16.
// Counted-vmcnt double buffer (R16).
template <int MODE>
__global__ __launch_bounds__(512) void k_gemm(
    const u16* __restrict__ Ah_g, const u16* __restrict__ Bh_g,
    const float* __restrict__ bias,
    u16* __restrict__ oQh, u16* __restrict__ oKh, u16* __restrict__ oVh,
    float* __restrict__ fout, int nbn) {
  // 64KB: buffer p at p*16384 u16: Ah[128][64] @0, Bh @8192.
  __shared__ u16 lds[32768];
  const int t = threadIdx.x;
  const int lane = t & 63, g = lane >> 4, cl = lane & 15;
  const int w = t >> 6;
  const int mi = blockIdx.x / nbn, ni = blockIdx.x % nbn;
  const int m0 = mi * 128, n0 = ni * 128;
  const int wr = (w >> 1) * 32, wc = (w & 1) * 64;

  f32x4 acc[2][4] = {};

#define STAGE_AB(kt_, pb_)                                                  \
  {                                                                         \
    const int k0__ = (kt_) * 64;                                            \
    const unsigned pb__ = (pb_);                                            \
    _Pragma("unroll") for (int j = 0; j < 4; ++j) {                         \
      int gs = j * 512 + t;                                                 \
      int tensor = gs >> 10;                                                \
      int s = gs & 1023;                                                    \
      int row = s >> 3;                                                     \
      int c = (s & 7) ^ (row & 7);                                          \
      const u16* src = tensor ? Bh_g + (n0 + row) * 1024 + k0__ + c * 8     \
                              : Ah_g + (m0 + row) * 1024 + k0__ + c * 8;    \
      async16(&lds[pb__ + (unsigned)(gs & ~63) * 8], src);                  \
    }                                                                       \
  }

#define COMPUTE_TILE(base_)                                                 \
  {                                                                         \
    const unsigned base__ = (base_);                                        \
    _Pragma("unroll") for (int ks = 0; ks < 2; ++ks) {                      \
      f16x8 af[2], bfr[4];                                                  \
      _Pragma("unroll") for (int fm = 0; fm < 2; ++fm) {                    \
        int rowL = wr + fm * 16 + cl;                                       \
        unsigned idx = base__ + rowL * 64 + (((4 * ks + g) ^ (rowL & 7)) * 8); \
        af[fm] = *(const f16x8*)&lds[idx];                                  \
      }                                                                     \
      _Pragma("unroll") for (int fn = 0; fn < 4; ++fn) {                    \
        int rowL = wc + fn * 16 + cl;                                       \
        unsigned idx = base__ + 8192 + rowL * 64 +                          \
                       (((4 * ks + g) ^ (rowL & 7)) * 8);                   \
        bfr[fn] = *(const f16x8*)&lds[idx];                                 \
      }                                                                     \
      _Pragma("unroll") for (int fm = 0; fm < 2; ++fm)                      \
        _Pragma("unroll") for (int fn = 0; fn < 4; ++fn)                    \
          acc[fm][fn] = MFMA16(af[fm], bfr[fn], acc[fm][fn]);               \
    }                                                                       \
  }

  STAGE_AB(0, 0u);
  STAGE_AB(1, 16384u);

  for (int kt = 0; kt < 15; ++kt) {
    asm volatile("s_waitcnt vmcnt(4)" ::: "memory");  // tile kt landed
    __builtin_amdgcn_sched_barrier(0);
    __builtin_amdgcn_s_barrier();
    __builtin_amdgcn_sched_barrier(0);
    const unsigned base = (kt & 1) ? 16384u : 0u;
    COMPUTE_TILE(base);
    asm volatile("s_waitcnt lgkmcnt(0)" ::: "memory");  // my ds_reads returned
    __builtin_amdgcn_sched_barrier(0);
    __builtin_amdgcn_s_barrier();                       // all waves done reading
    __builtin_amdgcn_sched_barrier(0);
    if (kt < 14) STAGE_AB(kt + 2, base);                // overwrite freed buffer
  }
  asm volatile("s_waitcnt vmcnt(0)" ::: "memory");
  __builtin_amdgcn_sched_barrier(0);
  __builtin_amdgcn_s_barrier();
  __builtin_amdgcn_sched_barrier(0);
  COMPUTE_TILE(16384u);
#undef STAGE_AB
#undef COMPUTE_TILE

  // epilogue
#pragma unroll
  for (int fm = 0; fm < 2; ++fm) {
#pragma unroll
    for (int fn = 0; fn < 4; ++fn) {
      int cc = n0 + wc + fn * 16 + cl;
      float bv = bias[cc];
      f32x4 a = acc[fm][fn];
#pragma unroll
      for (int r = 0; r < 4; ++r) {
        int rr = m0 + wr + fm * 16 + g * 4 + r;
        float v = a[r] + bv;
        if (MODE == 0) {
          int seg = cc >> 10, cm = cc & 1023;
          int h = cm >> 6, d = cm & 63;
          int b = rr >> 11, n = rr & 2047;
          int bh = b * 16 + h;
          if (seg == 0) {
            v *= 0.1803368801111204f;  // SCALE * log2(e): exp2-domain softmax
            oQh[(bh * 2048 + n) * 64 + d] = f2h(v);
          } else if (seg == 1) {
            oKh[(bh * 2048 + n) * 64 + d] = f2h(v);
          } else {
            oVh[(bh * 64 + d) * 2048 + n] = f2h(v);  // V transposed [bh][d][n]
          }
        } else {
          fout[rr * 1024 + cc] = v;
        }
      }
    }
  }
}

// ---------------- flash attention (swapped QK^T, base-2, no-max softmax) ----
// grid 512, 8 waves x 16 q-rows = 128 q-rows/block. KVBLK = 128 (2 sub-tiles).
// Counted-vmcnt double buffer over 32KB super-tiles (K0,V0,K1,V1 each [64][64]);
// per super-iter: vmcnt(4) -> barrier -> COMPUTE_KV x2 -> lgkmcnt(0)+barrier ->
// stage kts+2. P = exp2(st) (no max); pkrtz packing.
// LDS: 2 x 32KB + 8 x 2KB P = 80KB -> 2 blocks/CU (= grid).
__global__ __launch_bounds__(512, 4) void k_attn(
    const u16* __restrict__ Qh, const u16* __restrict__ Kh,
    const u16* __restrict__ Vh, u16* __restrict__ Oh) {
  // Buffer p (base = p*16384 u16): K0 @0 [64 key][64 d], V0t @4096 [64 d][64 key],
  // K1 @8192, V1t @12288. P per wave @32768 + w*1024 ([16 q][64 k]).
  __shared__ u16 lds[40960];
  const int t = threadIdx.x, w = t >> 6, lane = t & 63, g = lane >> 4, cl = lane & 15;
  int bid = (blockIdx.x & 7) * 64 + (blockIdx.x >> 3);  // same-bh blocks -> same XCD
  const int bh = bid >> 4, qt = bid & 15;
  const int n0 = qt * 128;
  const int PH = 32768 + w * 1024;

  // Q fragments (B operand; pre-scaled by SCALE*log2e)
  f16x8 qf[2];
  {
    int rg = bh * 2048 + n0 + w * 16 + cl;
#pragma unroll
    for (int ks = 0; ks < 2; ++ks)
      qf[ks] = *(const f16x8*)&Qh[rg * 64 + ks * 32 + g * 8];
  }

  f32x4 o[4] = {};
  f32x4 ps4 = {0.f, 0.f, 0.f, 0.f};  // per-lane partial row-sums
  const int bsrc = (lane & 48) | ((lane >> 2) & 12);  // lane with cl = 4g (same g)
  const int swz = (cl & 7) << 3;

  // stage super-tile kts (key-tiles 2*kts, 2*kts+1): K0,V0,K1,V1 (4KB regions)
#define STAGE_KV2(kts_, pbase_)                                            \
  {                                                                        \
    const int kt2__ = 2 * (kts_);                                          \
    const unsigned pb__ = (pbase_);                                        \
    _Pragma("unroll") for (int j = 0; j < 4; ++j) {                        \
      int gs = j * 512 + t;                                                \
      int tensor = gs >> 9, s = gs & 511, row = s >> 3;                    \
      int c = (s & 7) ^ (row & 7);                                         \
      int sub = tensor >> 1;          /* 0: key-tile kt2, 1: kt2+1 */      \
      const u16* src;                                                      \
      if ((tensor & 1) == 0)                                               \
        src = Kh + (bh * 2048 + (kt2__ + sub) * 64 + row) * 64 + c * 8;    \
      else                                                                 \
        src = Vh + (bh * 64 + row) * 2048 + (kt2__ + sub) * 64 + c * 8;    \
      async16(&lds[pb__ + (unsigned)(gs & ~63) * 8], src);                 \
    }                                                                      \
  }

  // one K/V sub-tile of compute (QK^T, no-max softmax, P roundtrip, PV)
#define COMPUTE_KV(base_)                                                   \
  {                                                                         \
    const unsigned base__ = (base_);                                        \
    f32x4 st[4] = {};                                                       \
    __builtin_amdgcn_s_setprio(1);                                          \
    _Pragma("unroll") for (int fn = 0; fn < 4; ++fn) {                      \
      int krow = fn * 16 + cl;                                              \
      _Pragma("unroll") for (int ks = 0; ks < 2; ++ks) {                    \
        unsigned idx = base__ + krow * 64 + (((4 * ks + g) ^ (krow & 7)) * 8); \
        f16x8 kf = *(const f16x8*)&lds[idx];                                \
        st[fn] = MFMA16(kf, qf[ks], st[fn]);                                \
      }                                                                     \
    }                                                                       \
    __builtin_amdgcn_s_setprio(0);                                          \
    unsigned upk[4][2];                                                     \
    _Pragma("unroll") for (int fn = 0; fn < 4; ++fn) {                      \
      float p0 = __builtin_amdgcn_exp2f(st[fn][0]);                         \
      float p1 = __builtin_amdgcn_exp2f(st[fn][1]);                         \
      float p2 = __builtin_amdgcn_exp2f(st[fn][2]);                         \
      float p3 = __builtin_amdgcn_exp2f(st[fn][3]);                         \
      ps4[0] += p0; ps4[1] += p1; ps4[2] += p2; ps4[3] += p3;               \
      upk[fn][0] = pkrtz(p0, p1);                                           \
      upk[fn][1] = pkrtz(p2, p3);                                           \
    }                                                                       \
    _Pragma("unroll") for (int fn = 0; fn < 4; ++fn) {                      \
      int addr = (cl * 64 + fn * 16 + 4 * g) ^ swz;                         \
      *(uint2*)&lds[PH + addr] = make_uint2(upk[fn][0], upk[fn][1]);        \
    }                                                                       \
    f16x8 pa[2];                                                            \
    _Pragma("unroll") for (int ks = 0; ks < 2; ++ks) {                      \
      int addr = (cl * 64 + ks * 32 + 8 * g) ^ swz;                         \
      pa[ks] = *(const f16x8*)&lds[PH + addr];                              \
    }                                                                       \
    __builtin_amdgcn_s_setprio(1);                                          \
    _Pragma("unroll") for (int fd = 0; fd < 4; ++fd) {                      \
      int vrow = fd * 16 + cl;                                              \
      _Pragma("unroll") for (int ks = 0; ks < 2; ++ks) {                    \
        unsigned idx = base__ + 4096 + vrow * 64 +                          \
                       (((4 * ks + g) ^ (vrow & 7)) * 8);                   \
        f16x8 vf = *(const f16x8*)&lds[idx];                                \
        o[fd] = MFMA16(pa[ks], vf, o[fd]);                                  \
      }                                                                     \
    }                                                                       \
    __builtin_amdgcn_s_setprio(0);                                          \
  }

  STAGE_KV2(0, 0u);
  STAGE_KV2(1, 16384u);

  for (int kts = 0; kts < 15; ++kts) {
    asm volatile("s_waitcnt vmcnt(4)" ::: "memory");  // super-tile kts landed
    __builtin_amdgcn_sched_barrier(0);
    __builtin_amdgcn_s_barrier();
    __builtin_amdgcn_sched_barrier(0);
    const unsigned base = (kts & 1) ? 16384u : 0u;
    COMPUTE_KV(base);          // key-tile 2*kts
    COMPUTE_KV(base + 8192u);  // key-tile 2*kts+1
    asm volatile("s_waitcnt lgkmcnt(0)" ::: "memory");  // my ds_reads returned
    __builtin_amdgcn_sched_barrier(0);
    __builtin_amdgcn_s_barrier();                       // all waves done reading
    __builtin_amdgcn_sched_barrier(0);
    if (kts < 14) STAGE_KV2(kts + 2, base);             // overwrite freed buffer
  }
  asm volatile("s_waitcnt vmcnt(0)" ::: "memory");
  __builtin_amdgcn_sched_barrier(0);
  __builtin_amdgcn_s_barrier();
  __builtin_amdgcn_sched_barrier(0);
  COMPUTE_KV(16384u);
  COMPUTE_KV(16384u + 8192u);
#undef STAGE_KV2
#undef COMPUTE_KV

  // final row sums: horizontal + cross-lane reduce, then normalize + write O
  float lrun = (ps4[0] + ps4[1]) + (ps4[2] + ps4[3]);
  lrun += __shfl_xor(lrun, 16);
  lrun += __shfl_xor(lrun, 32);
  const int b = bh >> 4, h = bh & 15;
  float l0 = __shfl(lrun, bsrc), l1 = __shfl(lrun, bsrc | 1);
  float l2 = __shfl(lrun, bsrc | 2), l3 = __shfl(lrun, bsrc | 3);
  float inv[4] = {1.0f / l0, 1.0f / l1, 1.0f / l2, 1.0f / l3};
#pragma unroll
  for (int fd = 0; fd < 4; ++fd)
#pragma unroll
    for (int r = 0; r < 4; ++r) {
      float v = o[fd][r] * inv[r];
      int rowg = b * 2048 + n0 + w * 16 + 4 * g + r;
      int colg = h * 64 + fd * 16 + cl;
      Oh[rowg * 1024 + colg] = f2h(v);
    }
}

extern "C" void kernel_launch(void* const* d_in, const int* in_sizes, int n_in,
                              void* d_out, int out_size, void* d_ws, size_t ws_size,
                              hipStream_t stream) {
  const float* x  = (const float*)d_in[0];
  const float* Wq = (const float*)d_in[1];
  const float* bq = (const float*)d_in[2];
  const float* Wp = (const float*)d_in[3];
  const float* bp = (const float*)d_in[4];
  float* out = (float*)d_out;
  char* ws = (char*)d_ws;

  u16* Xh  = (u16*)(ws + 0);         // 8MB, also Oh
  u16* Wqh = (u16*)(ws + 8388608);   // 6MB
  u16* Wph = (u16*)(ws + 14680064);  // 2MB
  u16* Qh  = (u16*)(ws + 16777216);  // 8MB
  u16* Kh  = (u16*)(ws + 25165824);  // 8MB
  u16* Vh  = (u16*)(ws + 33554432);  // 8MB -> end 40MB

  k_split_all<<<8192, 256, 0, stream>>>(x, Wq, Wp, Xh, Wqh, Wph);

  k_gemm<0><<<32 * 24, 512, 0, stream>>>(Xh, Wqh, bq, Qh, Kh, Vh, nullptr, 24);
  k_attn<<<512, 512, 0, stream>>>(Qh, Kh, Vh, Xh);
  k_gemm<1><<<32 * 8, 512, 0, stream>>>(Xh, Wph, bp,
                                        nullptr, nullptr, nullptr, out, 8);
}

// Round 20
// 122.051 us; speedup vs baseline: 1.0166x; 1.0166x over previous
//
#include <hip/hip_runtime.h>

// MHA forward: qkv GEMM -> flash attention -> proj GEMM. B=2,N=2048,C=1024,H=16,D=64.
// R20: QKV GEMM retiled 128x192 (k_gemmq): grid 32x16=512 = EXACTLY 2 blocks/CU
//      across 256 CUs (no scheduling tail; old 768-block grid ran 1.5 rounds).
//      Wave tile 32x96 (fm=2,fn=6): 24 MFMA per 16 ds_reads per iter. Same
//      counted-vmcnt skeleton as R16 (5 loads/thread -> vmcnt(5)). LDS 80KB.
//      proj keeps R16 kernel (grid 256 already packs). attn (R18/19) unchanged.

typedef unsigned short u16;
typedef __attribute__((ext_vector_type(8))) _Float16 f16x8;
typedef __attribute__((ext_vector_type(2))) __fp16 fp16x2;
typedef __attribute__((ext_vector_type(4))) float f32x4;

#define DEV static __device__ __forceinline__
#define MFMA16(a, b, c) __builtin_amdgcn_mfma_f32_16x16x32_f16(a, b, c, 0, 0, 0)

DEV u16 f2h(float f) { _Float16 h = (_Float16)f; return __builtin_bit_cast(u16, h); }
DEV float h2f(u16 u) { return (float)__builtin_bit_cast(_Float16, u); }
DEV unsigned pkrtz(float a, float b) {
  fp16x2 h2 = __builtin_amdgcn_cvt_pkrtz(a, b);
  return __builtin_bit_cast(unsigned, h2);
}

DEV void async16(u16* dst, const u16* src) {
  __builtin_amdgcn_global_load_lds(
      (const __attribute__((address_space(1))) unsigned int*)(const void*)src,
      (__attribute__((address_space(3))) unsigned int*)(void*)dst, 16, 0, 0);
}

// ---------------- split fp32 -> fp16 hi (all three inputs) ----------------
__global__ __launch_bounds__(256) void k_split_all(
    const float* __restrict__ x, const float* __restrict__ wq,
    const float* __restrict__ wp, u16* __restrict__ xh,
    u16* __restrict__ wqh, u16* __restrict__ wph) {
  int i = blockIdx.x * 256 + threadIdx.x;
  const float* src;
  u16* dh;
  int off;
  if (i < 1048576) { src = x;  dh = xh;  off = i; }
  else if (i < 1835008) { src = wq; dh = wqh; off = i - 1048576; }
  else { src = wp; dh = wph; off = i - 1835008; }
  float4 v = ((const float4*)src)[off];
  ushort4 h;
  h.x = f2h(v.x); h.y = f2h(v.y); h.z = f2h(v.z); h.w = f2h(v.w);
  ((ushort4*)dh)[off] = h;
}

// ---------------- QKV GEMM: 128x192 tile, BK=64, 8 waves (4x2, 32x96/wave) ----
// Counted-vmcnt double buffer; buffer = A[128][64] @0 (8192 u16) + B[192][64]
// @8192 (12288 u16) = 20480 u16 (40KB). Two buffers = 80KB LDS.
// grid = (4096/128) x (3072/192) = 32 x 16 = 512 blocks = 2/CU exactly.
__global__ __launch_bounds__(512) void k_gemmq(
    const u16* __restrict__ Ah_g, const u16* __restrict__ Bh_g,
    const float* __restrict__ bias,
    u16* __restrict__ oQh, u16* __restrict__ oKh, u16* __restrict__ oVh) {
  __shared__ u16 lds[40960];
  const int t = threadIdx.x;
  const int lane = t & 63, g = lane >> 4, cl = lane & 15;
  const int w = t >> 6;
  const int mi = blockIdx.x >> 4, ni = blockIdx.x & 15;
  const int m0 = mi * 128, n0 = ni * 192;
  const int wr = (w >> 1) * 32, wc = (w & 1) * 96;

  f32x4 acc[2][6] = {};

  // stage K-tile kt: 2560 chunks of 16B (A: [0,1024), B: [1024,2560)); 5/thread
#define STAGE_AB(kt_, pb_)                                                  \
  {                                                                         \
    const int k0__ = (kt_) * 64;                                            \
    const unsigned pb__ = (pb_);                                            \
    _Pragma("unroll") for (int j = 0; j < 5; ++j) {                         \
      int gs = j * 512 + t;                                                 \
      const u16* src;                                                       \
      if (gs < 1024) {                                                      \
        int row = gs >> 3;                                                  \
        int c = (gs & 7) ^ (row & 7);                                       \
        src = Ah_g + (m0 + row) * 1024 + k0__ + c * 8;                      \
      } else {                                                              \
        int s = gs - 1024;                                                  \
        int row = s >> 3;                                                   \
        int c = (s & 7) ^ (row & 7);                                        \
        src = Bh_g + (n0 + row) * 1024 + k0__ + c * 8;                      \
      }                                                                     \
      async16(&lds[pb__ + (unsigned)(gs & ~63) * 8], src);                  \
    }                                                                       \
  }

#define COMPUTE_TILE(base_)                                                 \
  {                                                                         \
    const unsigned base__ = (base_);                                        \
    _Pragma("unroll") for (int ks = 0; ks < 2; ++ks) {                      \
      f16x8 af[2], bfr[6];                                                  \
      _Pragma("unroll") for (int fm = 0; fm < 2; ++fm) {                    \
        int rowL = wr + fm * 16 + cl;                                       \
        unsigned idx = base__ + rowL * 64 + (((4 * ks + g) ^ (rowL & 7)) * 8); \
        af[fm] = *(const f16x8*)&lds[idx];                                  \
      }                                                                     \
      _Pragma("unroll") for (int fn = 0; fn < 6; ++fn) {                    \
        int rowL = wc + fn * 16 + cl;                                       \
        unsigned idx = base__ + 8192 + rowL * 64 +                          \
                       (((4 * ks + g) ^ (rowL & 7)) * 8);                   \
        bfr[fn] = *(const f16x8*)&lds[idx];                                 \
      }                                                                     \
      _Pragma("unroll") for (int fm = 0; fm < 2; ++fm)                      \
        _Pragma("unroll") for (int fn = 0; fn < 6; ++fn)                    \
          acc[fm][fn] = MFMA16(af[fm], bfr[fn], acc[fm][fn]);               \
    }                                                                       \
  }

  STAGE_AB(0, 0u);
  STAGE_AB(1, 20480u);

  for (int kt = 0; kt < 15; ++kt) {
    asm volatile("s_waitcnt vmcnt(5)" ::: "memory");  // tile kt landed
    __builtin_amdgcn_sched_barrier(0);
    __builtin_amdgcn_s_barrier();
    __builtin_amdgcn_sched_barrier(0);
    const unsigned base = (kt & 1) ? 20480u : 0u;
    COMPUTE_TILE(base);
    asm volatile("s_waitcnt lgkmcnt(0)" ::: "memory");  // my ds_reads returned
    __builtin_amdgcn_sched_barrier(0);
    __builtin_amdgcn_s_barrier();                       // all waves done reading
    __builtin_amdgcn_sched_barrier(0);
    if (kt < 14) STAGE_AB(kt + 2, base);                // overwrite freed buffer
  }
  asm volatile("s_waitcnt vmcnt(0)" ::: "memory");
  __builtin_amdgcn_sched_barrier(0);
  __builtin_amdgcn_s_barrier();
  __builtin_amdgcn_sched_barrier(0);
  COMPUTE_TILE(20480u);
#undef STAGE_AB
#undef COMPUTE_TILE

  // epilogue: route Q (scaled), K, V^T per element (cc may straddle segments)
#pragma unroll
  for (int fm = 0; fm < 2; ++fm) {
#pragma unroll
    for (int fn = 0; fn < 6; ++fn) {
      int cc = n0 + wc + fn * 16 + cl;
      float bv = bias[cc];
      f32x4 a = acc[fm][fn];
#pragma unroll
      for (int r = 0; r < 4; ++r) {
        int rr = m0 + wr + fm * 16 + g * 4 + r;
        float v = a[r] + bv;
        int seg = cc >> 10, cm = cc & 1023;
        int h = cm >> 6, d = cm & 63;
        int b = rr >> 11, n = rr & 2047;
        int bh = b * 16 + h;
        if (seg == 0) {
          v *= 0.1803368801111204f;  // SCALE * log2(e): exp2-domain softmax
          oQh[(bh * 2048 + n) * 64 + d] = f2h(v);
        } else if (seg == 1) {
          oKh[(bh * 2048 + n) * 64 + d] = f2h(v);
        } else {
          oVh[(bh * 64 + d) * 2048 + n] = f2h(v);  // V transposed [bh][d][n]
        }
      }
    }
  }
}

// ---------------- proj GEMM: 128x128 tile (R16 counted-vmcnt), fp32 out ------
__global__ __launch_bounds__(512) void k_gemm(
    const u16* __restrict__ Ah_g, const u16* __restrict__ Bh_g,
    const float* __restrict__ bias, float* __restrict__ fout, int nbn) {
  // 64KB: buffer p at p*16384 u16: Ah[128][64] @0, Bh @8192.
  __shared__ u16 lds[32768];
  const int t = threadIdx.x;
  const int lane = t & 63, g = lane >> 4, cl = lane & 15;
  const int w = t >> 6;
  const int mi = blockIdx.x / nbn, ni = blockIdx.x % nbn;
  const int m0 = mi * 128, n0 = ni * 128;
  const int wr = (w >> 1) * 32, wc = (w & 1) * 64;

  f32x4 acc[2][4] = {};

#define STAGE_AB(kt_, pb_)                                                  \
  {                                                                         \
    const int k0__ = (kt_) * 64;                                            \
    const unsigned pb__ = (pb_);                                            \
    _Pragma("unroll") for (int j = 0; j < 4; ++j) {                         \
      int gs = j * 512 + t;                                                 \
      int tensor = gs >> 10;                                                \
      int s = gs & 1023;                                                    \
      int row = s >> 3;                                                     \
      int c = (s & 7) ^ (row & 7);                                          \
      const u16* src = tensor ? Bh_g + (n0 + row) * 1024 + k0__ + c * 8     \
                              : Ah_g + (m0 + row) * 1024 + k0__ + c * 8;    \
      async16(&lds[pb__ + (unsigned)(gs & ~63) * 8], src);                  \
    }                                                                       \
  }

#define COMPUTE_TILE(base_)                                                 \
  {                                                                         \
    const unsigned base__ = (base_);                                        \
    _Pragma("unroll") for (int ks = 0; ks < 2; ++ks) {                      \
      f16x8 af[2], bfr[4];                                                  \
      _Pragma("unroll") for (int fm = 0; fm < 2; ++fm) {                    \
        int rowL = wr + fm * 16 + cl;                                       \
        unsigned idx = base__ + rowL * 64 + (((4 * ks + g) ^ (rowL & 7)) * 8); \
        af[fm] = *(const f16x8*)&lds[idx];                                  \
      }                                                                     \
      _Pragma("unroll") for (int fn = 0; fn < 4; ++fn) {                    \
        int rowL = wc + fn * 16 + cl;                                       \
        unsigned idx = base__ + 8192 + rowL * 64 +                          \
                       (((4 * ks + g) ^ (rowL & 7)) * 8);                   \
        bfr[fn] = *(const f16x8*)&lds[idx];                                 \
      }                                                                     \
      _Pragma("unroll") for (int fm = 0; fm < 2; ++fm)                      \
        _Pragma("unroll") for (int fn = 0; fn < 4; ++fn)                    \
          acc[fm][fn] = MFMA16(af[fm], bfr[fn], acc[fm][fn]);               \
    }                                                                       \
  }

  STAGE_AB(0, 0u);
  STAGE_AB(1, 16384u);

  for (int kt = 0; kt < 15; ++kt) {
    asm volatile("s_waitcnt vmcnt(4)" ::: "memory");
    __builtin_amdgcn_sched_barrier(0);
    __builtin_amdgcn_s_barrier();
    __builtin_amdgcn_sched_barrier(0);
    const unsigned base = (kt & 1) ? 16384u : 0u;
    COMPUTE_TILE(base);
    asm volatile("s_waitcnt lgkmcnt(0)" ::: "memory");
    __builtin_amdgcn_sched_barrier(0);
    __builtin_amdgcn_s_barrier();
    __builtin_amdgcn_sched_barrier(0);
    if (kt < 14) STAGE_AB(kt + 2, base);
  }
  asm volatile("s_waitcnt vmcnt(0)" ::: "memory");
  __builtin_amdgcn_sched_barrier(0);
  __builtin_amdgcn_s_barrier();
  __builtin_amdgcn_sched_barrier(0);
  COMPUTE_TILE(16384u);
#undef STAGE_AB
#undef COMPUTE_TILE

#pragma unroll
  for (int fm = 0; fm < 2; ++fm) {
#pragma unroll
    for (int fn = 0; fn < 4; ++fn) {
      int cc = n0 + wc + fn * 16 + cl;
      float bv = bias[cc];
      f32x4 a = acc[fm][fn];
#pragma unroll
      for (int r = 0; r < 4; ++r) {
        int rr = m0 + wr + fm * 16 + g * 4 + r;
        fout[rr * 1024 + cc] = a[r] + bv;
      }
    }
  }
}

// ---------------- flash attention (swapped QK^T, base-2, no-max softmax) ----
// grid 512, 8 waves x 16 q-rows. KVBLK=128 counted-vmcnt super-tiles (R19).
__global__ __launch_bounds__(512, 4) void k_attn(
    const u16* __restrict__ Qh, const u16* __restrict__ Kh,
    const u16* __restrict__ Vh, u16* __restrict__ Oh) {
  // Buffer p (base = p*16384 u16): K0 @0 [64 key][64 d], V0t @4096 [64 d][64 key],
  // K1 @8192, V1t @12288. P per wave @32768 + w*1024 ([16 q][64 k]).
  __shared__ u16 lds[40960];
  const int t = threadIdx.x, w = t >> 6, lane = t & 63, g = lane >> 4, cl = lane & 15;
  int bid = (blockIdx.x & 7) * 64 + (blockIdx.x >> 3);  // same-bh blocks -> same XCD
  const int bh = bid >> 4, qt = bid & 15;
  const int n0 = qt * 128;
  const int PH = 32768 + w * 1024;

  f16x8 qf[2];
  {
    int rg = bh * 2048 + n0 + w * 16 + cl;
#pragma unroll
    for (int ks = 0; ks < 2; ++ks)
      qf[ks] = *(const f16x8*)&Qh[rg * 64 + ks * 32 + g * 8];
  }

  f32x4 o[4] = {};
  f32x4 ps4 = {0.f, 0.f, 0.f, 0.f};
  const int bsrc = (lane & 48) | ((lane >> 2) & 12);
  const int swz = (cl & 7) << 3;

#define STAGE_KV2(kts_, pbase_)                                            \
  {                                                                        \
    const int kt2__ = 2 * (kts_);                                          \
    const unsigned pb__ = (pbase_);                                        \
    _Pragma("unroll") for (int j = 0; j < 4; ++j) {                        \
      int gs = j * 512 + t;                                                \
      int tensor = gs >> 9, s = gs & 511, row = s >> 3;                    \
      int c = (s & 7) ^ (row & 7);                                         \
      int sub = tensor >> 1;                                               \
      const u16* src;                                                      \
      if ((tensor & 1) == 0)                                               \
        src = Kh + (bh * 2048 + (kt2__ + sub) * 64 + row) * 64 + c * 8;    \
      else                                                                 \
        src = Vh + (bh * 64 + row) * 2048 + (kt2__ + sub) * 64 + c * 8;    \
      async16(&lds[pb__ + (unsigned)(gs & ~63) * 8], src);                 \
    }                                                                      \
  }

#define COMPUTE_KV(base_)                                                   \
  {                                                                         \
    const unsigned base__ = (base_);                                        \
    f32x4 st[4] = {};                                                       \
    __builtin_amdgcn_s_setprio(1);                                          \
    _Pragma("unroll") for (int fn = 0; fn < 4; ++fn) {                      \
      int krow = fn * 16 + cl;                                              \
      _Pragma("unroll") for (int ks = 0; ks < 2; ++ks) {                    \
        unsigned idx = base__ + krow * 64 + (((4 * ks + g) ^ (krow & 7)) * 8); \
        f16x8 kf = *(const f16x8*)&lds[idx];                                \
        st[fn] = MFMA16(kf, qf[ks], st[fn]);                                \
      }                                                                     \
    }                                                                       \
    __builtin_amdgcn_s_setprio(0);                                          \
    unsigned upk[4][2];                                                     \
    _Pragma("unroll") for (int fn = 0; fn < 4; ++fn) {                      \
      float p0 = __builtin_amdgcn_exp2f(st[fn][0]);                         \
      float p1 = __builtin_amdgcn_exp2f(st[fn][1]);                         \
      float p2 = __builtin_amdgcn_exp2f(st[fn][2]);                         \
      float p3 = __builtin_amdgcn_exp2f(st[fn][3]);                         \
      ps4[0] += p0; ps4[1] += p1; ps4[2] += p2; ps4[3] += p3;               \
      upk[fn][0] = pkrtz(p0, p1);                                           \
      upk[fn][1] = pkrtz(p2, p3);                                           \
    }                                                                       \
    _Pragma("unroll") for (int fn = 0; fn < 4; ++fn) {                      \
      int addr = (cl * 64 + fn * 16 + 4 * g) ^ swz;                         \
      *(uint2*)&lds[PH + addr] = make_uint2(upk[fn][0], upk[fn][1]);        \
    }                                                                       \
    f16x8 pa[2];                                                            \
    _Pragma("unroll") for (int ks = 0; ks < 2; ++ks) {                      \
      int addr = (cl * 64 + ks * 32 + 8 * g) ^ swz;                         \
      pa[ks] = *(const f16x8*)&lds[PH + addr];                              \
    }                                                                       \
    __builtin_amdgcn_s_setprio(1);                                          \
    _Pragma("unroll") for (int fd = 0; fd < 4; ++fd) {                      \
      int vrow = fd * 16 + cl;                                              \
      _Pragma("unroll") for (int ks = 0; ks < 2; ++ks) {                    \
        unsigned idx = base__ + 4096 + vrow * 64 +                          \
                       (((4 * ks + g) ^ (vrow & 7)) * 8);                   \
        f16x8 vf = *(const f16x8*)&lds[idx];                                \
        o[fd] = MFMA16(pa[ks], vf, o[fd]);                                  \
      }                                                                     \
    }                                                                       \
    __builtin_amdgcn_s_setprio(0);                                          \
  }

  STAGE_KV2(0, 0u);
  STAGE_KV2(1, 16384u);

  for (int kts = 0; kts < 15; ++kts) {
    asm volatile("s_waitcnt vmcnt(4)" ::: "memory");
    __builtin_amdgcn_sched_barrier(0);
    __builtin_amdgcn_s_barrier();
    __builtin_amdgcn_sched_barrier(0);
    const unsigned base = (kts & 1) ? 16384u : 0u;
    COMPUTE_KV(base);
    COMPUTE_KV(base + 8192u);
    asm volatile("s_waitcnt lgkmcnt(0)" ::: "memory");
    __builtin_amdgcn_sched_barrier(0);
    __builtin_amdgcn_s_barrier();
    __builtin_amdgcn_sched_barrier(0);
    if (kts < 14) STAGE_KV2(kts + 2, base);
  }
  asm volatile("s_waitcnt vmcnt(0)" ::: "memory");
  __builtin_amdgcn_sched_barrier(0);
  __builtin_amdgcn_s_barrier();
  __builtin_amdgcn_sched_barrier(0);
  COMPUTE_KV(16384u);
  COMPUTE_KV(16384u + 8192u);
#undef STAGE_KV2
#undef COMPUTE_KV

  float lrun = (ps4[0] + ps4[1]) + (ps4[2] + ps4[3]);
  lrun += __shfl_xor(lrun, 16);
  lrun += __shfl_xor(lrun, 32);
  const int b = bh >> 4, h = bh & 15;
  float l0 = __shfl(lrun, bsrc), l1 = __shfl(lrun, bsrc | 1);
  float l2 = __shfl(lrun, bsrc | 2), l3 = __shfl(lrun, bsrc | 3);
  float inv[4] = {1.0f / l0, 1.0f / l1, 1.0f / l2, 1.0f / l3};
#pragma unroll
  for (int fd = 0; fd < 4; ++fd)
#pragma unroll
    for (int r = 0; r < 4; ++r) {
      float v = o[fd][r] * inv[r];
      int rowg = b * 2048 + n0 + w * 16 + 4 * g + r;
      int colg = h * 64 + fd * 16 + cl;
      Oh[rowg * 1024 + colg] = f2h(v);
    }
}

extern "C" void kernel_launch(void* const* d_in, const int* in_sizes, int n_in,
                              void* d_out, int out_size, void* d_ws, size_t ws_size,
                              hipStream_t stream) {
  const float* x  = (const float*)d_in[0];
  const float* Wq = (const float*)d_in[1];
  const float* bq = (const float*)d_in[2];
  const float* Wp = (const float*)d_in[3];
  const float* bp = (const float*)d_in[4];
  float* out = (float*)d_out;
  char* ws = (char*)d_ws;

  u16* Xh  = (u16*)(ws + 0);         // 8MB, also Oh
  u16* Wqh = (u16*)(ws + 8388608);   // 6MB
  u16* Wph = (u16*)(ws + 14680064);  // 2MB
  u16* Qh  = (u16*)(ws + 16777216);  // 8MB
  u16* Kh  = (u16*)(ws + 25165824);  // 8MB
  u16* Vh  = (u16*)(ws + 33554432);  // 8MB -> end 40MB

  k_split_all<<<8192, 256, 0, stream>>>(x, Wq, Wp, Xh, Wqh, Wph);

  k_gemmq<<<512, 512, 0, stream>>>(Xh, Wqh, bq, Qh, Kh, Vh);
  k_attn<<<512, 512, 0, stream>>>(Qh, Kh, Vh, Xh);
  k_gemm<<<32 * 8, 512, 0, stream>>>(Xh, Wph, bp, out, 8);
}

// Round 21
// 120.538 us; speedup vs baseline: 1.0293x; 1.0126x over previous
//
#include <hip/hip_runtime.h>

// MHA forward: qkv GEMM -> flash attention -> proj GEMM. B=2,N=2048,C=1024,H=16,D=64.
// R21: (a) attn fm=2 under counted-vmcnt: 8 waves x 32 q-rows (grid 256), each
//      K/V fragment feeds 2 MFMA -> per-row LDS traffic 1.25->0.75 KB. 96KB LDS.
//      (b) proj retiled 64x128 (grid 512 = 2 blocks/CU, 16 waves/CU, vmcnt(3)).
//      QKV (R20 128x192) and split unchanged.

typedef unsigned short u16;
typedef __attribute__((ext_vector_type(8))) _Float16 f16x8;
typedef __attribute__((ext_vector_type(2))) __fp16 fp16x2;
typedef __attribute__((ext_vector_type(4))) float f32x4;

#define DEV static __device__ __forceinline__
#define MFMA16(a, b, c) __builtin_amdgcn_mfma_f32_16x16x32_f16(a, b, c, 0, 0, 0)

DEV u16 f2h(float f) { _Float16 h = (_Float16)f; return __builtin_bit_cast(u16, h); }
DEV float h2f(u16 u) { return (float)__builtin_bit_cast(_Float16, u); }
DEV unsigned pkrtz(float a, float b) {
  fp16x2 h2 = __builtin_amdgcn_cvt_pkrtz(a, b);
  return __builtin_bit_cast(unsigned, h2);
}

DEV void async16(u16* dst, const u16* src) {
  __builtin_amdgcn_global_load_lds(
      (const __attribute__((address_space(1))) unsigned int*)(const void*)src,
      (__attribute__((address_space(3))) unsigned int*)(void*)dst, 16, 0, 0);
}

// ---------------- split fp32 -> fp16 hi (all three inputs) ----------------
__global__ __launch_bounds__(256) void k_split_all(
    const float* __restrict__ x, const float* __restrict__ wq,
    const float* __restrict__ wp, u16* __restrict__ xh,
    u16* __restrict__ wqh, u16* __restrict__ wph) {
  int i = blockIdx.x * 256 + threadIdx.x;
  const float* src;
  u16* dh;
  int off;
  if (i < 1048576) { src = x;  dh = xh;  off = i; }
  else if (i < 1835008) { src = wq; dh = wqh; off = i - 1048576; }
  else { src = wp; dh = wph; off = i - 1835008; }
  float4 v = ((const float4*)src)[off];
  ushort4 h;
  h.x = f2h(v.x); h.y = f2h(v.y); h.z = f2h(v.z); h.w = f2h(v.w);
  ((ushort4*)dh)[off] = h;
}

// ---------------- QKV GEMM: 128x192 tile, BK=64, 8 waves (4x2, 32x96/wave) ----
// Counted-vmcnt double buffer (R20). grid 512 = 2 blocks/CU exactly.
__global__ __launch_bounds__(512) void k_gemmq(
    const u16* __restrict__ Ah_g, const u16* __restrict__ Bh_g,
    const float* __restrict__ bias,
    u16* __restrict__ oQh, u16* __restrict__ oKh, u16* __restrict__ oVh) {
  __shared__ u16 lds[40960];
  const int t = threadIdx.x;
  const int lane = t & 63, g = lane >> 4, cl = lane & 15;
  const int w = t >> 6;
  const int mi = blockIdx.x >> 4, ni = blockIdx.x & 15;
  const int m0 = mi * 128, n0 = ni * 192;
  const int wr = (w >> 1) * 32, wc = (w & 1) * 96;

  f32x4 acc[2][6] = {};

#define STAGE_ABQ(kt_, pb_)                                                 \
  {                                                                         \
    const int k0__ = (kt_) * 64;                                            \
    const unsigned pb__ = (pb_);                                            \
    _Pragma("unroll") for (int j = 0; j < 5; ++j) {                         \
      int gs = j * 512 + t;                                                 \
      const u16* src;                                                       \
      if (gs < 1024) {                                                      \
        int row = gs >> 3;                                                  \
        int c = (gs & 7) ^ (row & 7);                                       \
        src = Ah_g + (m0 + row) * 1024 + k0__ + c * 8;                      \
      } else {                                                              \
        int s = gs - 1024;                                                  \
        int row = s >> 3;                                                   \
        int c = (s & 7) ^ (row & 7);                                        \
        src = Bh_g + (n0 + row) * 1024 + k0__ + c * 8;                      \
      }                                                                     \
      async16(&lds[pb__ + (unsigned)(gs & ~63) * 8], src);                  \
    }                                                                       \
  }

#define COMPUTE_TILEQ(base_)                                                \
  {                                                                         \
    const unsigned base__ = (base_);                                        \
    _Pragma("unroll") for (int ks = 0; ks < 2; ++ks) {                      \
      f16x8 af[2], bfr[6];                                                  \
      _Pragma("unroll") for (int fm = 0; fm < 2; ++fm) {                    \
        int rowL = wr + fm * 16 + cl;                                       \
        unsigned idx = base__ + rowL * 64 + (((4 * ks + g) ^ (rowL & 7)) * 8); \
        af[fm] = *(const f16x8*)&lds[idx];                                  \
      }                                                                     \
      _Pragma("unroll") for (int fn = 0; fn < 6; ++fn) {                    \
        int rowL = wc + fn * 16 + cl;                                       \
        unsigned idx = base__ + 8192 + rowL * 64 +                          \
                       (((4 * ks + g) ^ (rowL & 7)) * 8);                   \
        bfr[fn] = *(const f16x8*)&lds[idx];                                 \
      }                                                                     \
      _Pragma("unroll") for (int fm = 0; fm < 2; ++fm)                      \
        _Pragma("unroll") for (int fn = 0; fn < 6; ++fn)                    \
          acc[fm][fn] = MFMA16(af[fm], bfr[fn], acc[fm][fn]);               \
    }                                                                       \
  }

  STAGE_ABQ(0, 0u);
  STAGE_ABQ(1, 20480u);

  for (int kt = 0; kt < 15; ++kt) {
    asm volatile("s_waitcnt vmcnt(5)" ::: "memory");
    __builtin_amdgcn_sched_barrier(0);
    __builtin_amdgcn_s_barrier();
    __builtin_amdgcn_sched_barrier(0);
    const unsigned base = (kt & 1) ? 20480u : 0u;
    COMPUTE_TILEQ(base);
    asm volatile("s_waitcnt lgkmcnt(0)" ::: "memory");
    __builtin_amdgcn_sched_barrier(0);
    __builtin_amdgcn_s_barrier();
    __builtin_amdgcn_sched_barrier(0);
    if (kt < 14) STAGE_ABQ(kt + 2, base);
  }
  asm volatile("s_waitcnt vmcnt(0)" ::: "memory");
  __builtin_amdgcn_sched_barrier(0);
  __builtin_amdgcn_s_barrier();
  __builtin_amdgcn_sched_barrier(0);
  COMPUTE_TILEQ(20480u);
#undef STAGE_ABQ
#undef COMPUTE_TILEQ

#pragma unroll
  for (int fm = 0; fm < 2; ++fm) {
#pragma unroll
    for (int fn = 0; fn < 6; ++fn) {
      int cc = n0 + wc + fn * 16 + cl;
      float bv = bias[cc];
      f32x4 a = acc[fm][fn];
#pragma unroll
      for (int r = 0; r < 4; ++r) {
        int rr = m0 + wr + fm * 16 + g * 4 + r;
        float v = a[r] + bv;
        int seg = cc >> 10, cm = cc & 1023;
        int h = cm >> 6, d = cm & 63;
        int b = rr >> 11, n = rr & 2047;
        int bh = b * 16 + h;
        if (seg == 0) {
          v *= 0.1803368801111204f;  // SCALE * log2(e): exp2-domain softmax
          oQh[(bh * 2048 + n) * 64 + d] = f2h(v);
        } else if (seg == 1) {
          oKh[(bh * 2048 + n) * 64 + d] = f2h(v);
        } else {
          oVh[(bh * 64 + d) * 2048 + n] = f2h(v);  // V transposed [bh][d][n]
        }
      }
    }
  }
}

// ---------------- proj GEMM: 64x128 tile, 8 waves (2x4, 32x32/wave), fp32 out -
// grid 64x8 = 512 blocks = 2 blocks/CU (16 waves/CU). Counted-vmcnt dbuf,
// buffer = A[64][64] @0 (4096 u16) + B[128][64] @4096 (8192 u16) = 24KB.
__global__ __launch_bounds__(512) void k_gemm(
    const u16* __restrict__ Ah_g, const u16* __restrict__ Bh_g,
    const float* __restrict__ bias, float* __restrict__ fout) {
  __shared__ u16 lds[24576];
  const int t = threadIdx.x;
  const int lane = t & 63, g = lane >> 4, cl = lane & 15;
  const int w = t >> 6;
  const int mi = blockIdx.x >> 3, ni = blockIdx.x & 7;
  const int m0 = mi * 64, n0 = ni * 128;
  const int wr = (w >> 2) * 32, wc = (w & 3) * 32;

  f32x4 acc[2][2] = {};

#define STAGE_ABP(kt_, pb_)                                                 \
  {                                                                         \
    const int k0__ = (kt_) * 64;                                            \
    const unsigned pb__ = (pb_);                                            \
    _Pragma("unroll") for (int j = 0; j < 3; ++j) {                         \
      int gs = j * 512 + t;                                                 \
      const u16* src;                                                       \
      if (gs < 512) {                                                       \
        int row = gs >> 3;                                                  \
        int c = (gs & 7) ^ (row & 7);                                       \
        src = Ah_g + (m0 + row) * 1024 + k0__ + c * 8;                      \
      } else {                                                              \
        int s = gs - 512;                                                   \
        int row = s >> 3;                                                   \
        int c = (s & 7) ^ (row & 7);                                        \
        src = Bh_g + (n0 + row) * 1024 + k0__ + c * 8;                      \
      }                                                                     \
      async16(&lds[pb__ + (unsigned)(gs & ~63) * 8], src);                  \
    }                                                                       \
  }

#define COMPUTE_TILEP(base_)                                                \
  {                                                                         \
    const unsigned base__ = (base_);                                        \
    _Pragma("unroll") for (int ks = 0; ks < 2; ++ks) {                      \
      f16x8 af[2], bfr[2];                                                  \
      _Pragma("unroll") for (int fm = 0; fm < 2; ++fm) {                    \
        int rowL = wr + fm * 16 + cl;                                       \
        unsigned idx = base__ + rowL * 64 + (((4 * ks + g) ^ (rowL & 7)) * 8); \
        af[fm] = *(const f16x8*)&lds[idx];                                  \
      }                                                                     \
      _Pragma("unroll") for (int fn = 0; fn < 2; ++fn) {                    \
        int rowL = wc + fn * 16 + cl;                                       \
        unsigned idx = base__ + 4096 + rowL * 64 +                          \
                       (((4 * ks + g) ^ (rowL & 7)) * 8);                   \
        bfr[fn] = *(const f16x8*)&lds[idx];                                 \
      }                                                                     \
      _Pragma("unroll") for (int fm = 0; fm < 2; ++fm)                      \
        _Pragma("unroll") for (int fn = 0; fn < 2; ++fn)                    \
          acc[fm][fn] = MFMA16(af[fm], bfr[fn], acc[fm][fn]);               \
    }                                                                       \
  }

  STAGE_ABP(0, 0u);
  STAGE_ABP(1, 12288u);

  for (int kt = 0; kt < 15; ++kt) {
    asm volatile("s_waitcnt vmcnt(3)" ::: "memory");
    __builtin_amdgcn_sched_barrier(0);
    __builtin_amdgcn_s_barrier();
    __builtin_amdgcn_sched_barrier(0);
    const unsigned base = (kt & 1) ? 12288u : 0u;
    COMPUTE_TILEP(base);
    asm volatile("s_waitcnt lgkmcnt(0)" ::: "memory");
    __builtin_amdgcn_sched_barrier(0);
    __builtin_amdgcn_s_barrier();
    __builtin_amdgcn_sched_barrier(0);
    if (kt < 14) STAGE_ABP(kt + 2, base);
  }
  asm volatile("s_waitcnt vmcnt(0)" ::: "memory");
  __builtin_amdgcn_sched_barrier(0);
  __builtin_amdgcn_s_barrier();
  __builtin_amdgcn_sched_barrier(0);
  COMPUTE_TILEP(12288u);
#undef STAGE_ABP
#undef COMPUTE_TILEP

#pragma unroll
  for (int fm = 0; fm < 2; ++fm) {
#pragma unroll
    for (int fn = 0; fn < 2; ++fn) {
      int cc = n0 + wc + fn * 16 + cl;
      float bv = bias[cc];
      f32x4 a = acc[fm][fn];
#pragma unroll
      for (int r = 0; r < 4; ++r) {
        int rr = m0 + wr + fm * 16 + g * 4 + r;
        fout[rr * 1024 + cc] = a[r] + bv;
      }
    }
  }
}

// ---------------- flash attention (swapped QK^T, base-2, no-max softmax) ----
// grid 256, 8 waves x 32 q-rows = 256 q-rows/block. KVBLK=128 counted-vmcnt
// super-tiles. fm=2: each K/V fragment feeds 2 MFMA (per-row LDS traffic -40%).
// LDS: 2 x 32KB K/V + 8 x 4KB P = 96KB -> 1 block/CU.
__global__ __launch_bounds__(512) void k_attn(
    const u16* __restrict__ Qh, const u16* __restrict__ Kh,
    const u16* __restrict__ Vh, u16* __restrict__ Oh) {
  // Buffer p (base = p*16384 u16): K0 @0 [64 key][64 d], V0t @4096 [64 d][64 key],
  // K1 @8192, V1t @12288. P per wave @32768 + w*2048 ([32 q][64 k]).
  __shared__ u16 lds[49152];
  const int t = threadIdx.x, w = t >> 6, lane = t & 63, g = lane >> 4, cl = lane & 15;
  int bid = (blockIdx.x & 7) * 32 + (blockIdx.x >> 3);  // same-bh blocks -> same XCD
  const int bh = bid >> 3, qt = bid & 7;
  const int n0 = qt * 256;
  const int PH = 32768 + w * 2048;

  // Q fragments (B operand; pre-scaled by SCALE*log2e); wave owns rows
  // n0 + w*32 + fm*16 + 0..15.
  f16x8 qf[2][2];
#pragma unroll
  for (int fm = 0; fm < 2; ++fm) {
    int rg = bh * 2048 + n0 + w * 32 + fm * 16 + cl;
#pragma unroll
    for (int ks = 0; ks < 2; ++ks)
      qf[fm][ks] = *(const f16x8*)&Qh[rg * 64 + ks * 32 + g * 8];
  }

  f32x4 o[2][4] = {};
  f32x4 ps4[2] = {{0.f, 0.f, 0.f, 0.f}, {0.f, 0.f, 0.f, 0.f}};
  const int bsrc = (lane & 48) | ((lane >> 2) & 12);  // lane with cl = 4g (same g)

#define STAGE_KV2(kts_, pbase_)                                            \
  {                                                                        \
    const int kt2__ = 2 * (kts_);                                          \
    const unsigned pb__ = (pbase_);                                        \
    _Pragma("unroll") for (int j = 0; j < 4; ++j) {                        \
      int gs = j * 512 + t;                                                \
      int tensor = gs >> 9, s = gs & 511, row = s >> 3;                    \
      int c = (s & 7) ^ (row & 7);                                         \
      int sub = tensor >> 1;                                               \
      const u16* src;                                                      \
      if ((tensor & 1) == 0)                                               \
        src = Kh + (bh * 2048 + (kt2__ + sub) * 64 + row) * 64 + c * 8;    \
      else                                                                 \
        src = Vh + (bh * 64 + row) * 2048 + (kt2__ + sub) * 64 + c * 8;    \
      async16(&lds[pb__ + (unsigned)(gs & ~63) * 8], src);                 \
    }                                                                      \
  }

  // one K/V sub-tile: QK^T (fm=2), no-max softmax, P roundtrip, PV (fm=2)
#define COMPUTE_KV(base_)                                                   \
  {                                                                         \
    const unsigned base__ = (base_);                                        \
    f32x4 st[2][4] = {};                                                    \
    __builtin_amdgcn_s_setprio(1);                                          \
    _Pragma("unroll") for (int fn = 0; fn < 4; ++fn) {                      \
      int krow = fn * 16 + cl;                                              \
      _Pragma("unroll") for (int ks = 0; ks < 2; ++ks) {                    \
        unsigned idx = base__ + krow * 64 + (((4 * ks + g) ^ (krow & 7)) * 8); \
        f16x8 kf = *(const f16x8*)&lds[idx];                                \
        _Pragma("unroll") for (int fm = 0; fm < 2; ++fm)                    \
          st[fm][fn] = MFMA16(kf, qf[fm][ks], st[fm][fn]);                  \
      }                                                                     \
    }                                                                       \
    __builtin_amdgcn_s_setprio(0);                                          \
    _Pragma("unroll") for (int fm = 0; fm < 2; ++fm) {                      \
      unsigned upk[4][2];                                                   \
      _Pragma("unroll") for (int fn = 0; fn < 4; ++fn) {                    \
        float p0 = __builtin_amdgcn_exp2f(st[fm][fn][0]);                   \
        float p1 = __builtin_amdgcn_exp2f(st[fm][fn][1]);                   \
        float p2 = __builtin_amdgcn_exp2f(st[fm][fn][2]);                   \
        float p3 = __builtin_amdgcn_exp2f(st[fm][fn][3]);                   \
        ps4[fm][0] += p0; ps4[fm][1] += p1;                                 \
        ps4[fm][2] += p2; ps4[fm][3] += p3;                                 \
        upk[fn][0] = pkrtz(p0, p1);                                         \
        upk[fn][1] = pkrtz(p2, p3);                                         \
      }                                                                     \
      int rq = fm * 16 + cl;                                                \
      int swz2 = (rq & 7) << 3;                                             \
      _Pragma("unroll") for (int fn = 0; fn < 4; ++fn) {                    \
        int addr = (rq * 64 + fn * 16 + 4 * g) ^ swz2;                      \
        *(uint2*)&lds[PH + addr] = make_uint2(upk[fn][0], upk[fn][1]);      \
      }                                                                     \
    }                                                                       \
    f16x8 pa[2][2];                                                         \
    _Pragma("unroll") for (int fm = 0; fm < 2; ++fm) {                      \
      int rq = fm * 16 + cl;                                                \
      int swz2 = (rq & 7) << 3;                                             \
      _Pragma("unroll") for (int ks = 0; ks < 2; ++ks) {                    \
        int addr = (rq * 64 + ks * 32 + 8 * g) ^ swz2;                      \
        pa[fm][ks] = *(const f16x8*)&lds[PH + addr];                        \
      }                                                                     \
    }                                                                       \
    __builtin_amdgcn_s_setprio(1);                                          \
    _Pragma("unroll") for (int fd = 0; fd < 4; ++fd) {                      \
      int vrow = fd * 16 + cl;                                              \
      _Pragma("unroll") for (int ks = 0; ks < 2; ++ks) {                    \
        unsigned idx = base__ + 4096 + vrow * 64 +                          \
                       (((4 * ks + g) ^ (vrow & 7)) * 8);                   \
        f16x8 vf = *(const f16x8*)&lds[idx];                                \
        _Pragma("unroll") for (int fm = 0; fm < 2; ++fm)                    \
          o[fm][fd] = MFMA16(pa[fm][ks], vf, o[fm][fd]);                    \
      }                                                                     \
    }                                                                       \
    __builtin_amdgcn_s_setprio(0);                                          \
  }

  STAGE_KV2(0, 0u);
  STAGE_KV2(1, 16384u);

  for (int kts = 0; kts < 15; ++kts) {
    asm volatile("s_waitcnt vmcnt(4)" ::: "memory");
    __builtin_amdgcn_sched_barrier(0);
    __builtin_amdgcn_s_barrier();
    __builtin_amdgcn_sched_barrier(0);
    const unsigned base = (kts & 1) ? 16384u : 0u;
    COMPUTE_KV(base);
    COMPUTE_KV(base + 8192u);
    asm volatile("s_waitcnt lgkmcnt(0)" ::: "memory");
    __builtin_amdgcn_sched_barrier(0);
    __builtin_amdgcn_s_barrier();
    __builtin_amdgcn_sched_barrier(0);
    if (kts < 14) STAGE_KV2(kts + 2, base);
  }
  asm volatile("s_waitcnt vmcnt(0)" ::: "memory");
  __builtin_amdgcn_sched_barrier(0);
  __builtin_amdgcn_s_barrier();
  __builtin_amdgcn_sched_barrier(0);
  COMPUTE_KV(16384u);
  COMPUTE_KV(16384u + 8192u);
#undef STAGE_KV2
#undef COMPUTE_KV

  // final row sums + normalize + write O (fp16, [token][h*64+d])
  const int b = bh >> 4, h = bh & 15;
#pragma unroll
  for (int fm = 0; fm < 2; ++fm) {
    float lrun = (ps4[fm][0] + ps4[fm][1]) + (ps4[fm][2] + ps4[fm][3]);
    lrun += __shfl_xor(lrun, 16);
    lrun += __shfl_xor(lrun, 32);
    float l0 = __shfl(lrun, bsrc), l1 = __shfl(lrun, bsrc | 1);
    float l2 = __shfl(lrun, bsrc | 2), l3 = __shfl(lrun, bsrc | 3);
    float inv[4] = {1.0f / l0, 1.0f / l1, 1.0f / l2, 1.0f / l3};
#pragma unroll
    for (int fd = 0; fd < 4; ++fd)
#pragma unroll
      for (int r = 0; r < 4; ++r) {
        float v = o[fm][fd][r] * inv[r];
        int rowg = b * 2048 + n0 + w * 32 + fm * 16 + 4 * g + r;
        int colg = h * 64 + fd * 16 + cl;
        Oh[rowg * 1024 + colg] = f2h(v);
      }
  }
}

extern "C" void kernel_launch(void* const* d_in, const int* in_sizes, int n_in,
                              void* d_out, int out_size, void* d_ws, size_t ws_size,
                              hipStream_t stream) {
  const float* x  = (const float*)d_in[0];
  const float* Wq = (const float*)d_in[1];
  const float* bq = (const float*)d_in[2];
  const float* Wp = (const float*)d_in[3];
  const float* bp = (const float*)d_in[4];
  float* out = (float*)d_out;
  char* ws = (char*)d_ws;

  u16* Xh  = (u16*)(ws + 0);         // 8MB, also Oh
  u16* Wqh = (u16*)(ws + 8388608);   // 6MB
  u16* Wph = (u16*)(ws + 14680064);  // 2MB
  u16* Qh  = (u16*)(ws + 16777216);  // 8MB
  u16* Kh  = (u16*)(ws + 25165824);  // 8MB
  u16* Vh  = (u16*)(ws + 33554432);  // 8MB -> end 40MB

  k_split_all<<<8192, 256, 0, stream>>>(x, Wq, Wp, Xh, Wqh, Wph);

  k_gemmq<<<512, 512, 0, stream>>>(Xh, Wqh, bq, Qh, Kh, Vh);
  k_attn<<<256, 512, 0, stream>>>(Qh, Kh, Vh, Xh);
  k_gemm<<<512, 512, 0, stream>>>(Xh, Wph, bp, out);
}